// Round 11
// baseline (523.522 us; speedup 1.0000x reference)
//
#include <hip/hip_runtime.h>
#include <math.h>

#define EMB 64
#define MAXREL 32

typedef short bf16x8 __attribute__((ext_vector_type(8)));
typedef float f32x4 __attribute__((ext_vector_type(4)));

__device__ __forceinline__ short f2bf(float f) {
    unsigned u = __float_as_uint(f);
    u += 0x7FFFu + ((u >> 16) & 1u);   // RNE
    return (short)(u >> 16);
}

#if __has_builtin(__builtin_amdgcn_cvt_pk_bf16_f32)
__device__ __forceinline__ short2 cvt2(float a, float b) {
    return __builtin_bit_cast(short2, __builtin_amdgcn_cvt_pk_bf16_f32(a, b));
}
#else
__device__ __forceinline__ short2 cvt2(float a, float b) {
    return make_short2(f2bf(a), f2bf(b));
}
#endif

// bf16 pair expansion from a packed dword (elem0 = low 16, elem1 = high 16)
__device__ __forceinline__ float lo_bf(unsigned d) { return __uint_as_float(d << 16); }
__device__ __forceinline__ float hi_bf(unsigned d) { return __uint_as_float(d & 0xffff0000u); }
__device__ __forceinline__ float bfs(short s) {
    return __uint_as_float(((unsigned)(unsigned short)s) << 16);
}

// A-fragment = bf16( bf16agg ⊙ rel_f32 )
__device__ __forceinline__ bf16x8 pack8bf(uint4 U, float4 r0, float4 r1) {
    short2 c0 = cvt2(lo_bf(U.x) * r0.x, hi_bf(U.x) * r0.y);
    short2 c1 = cvt2(lo_bf(U.y) * r0.z, hi_bf(U.y) * r0.w);
    short2 c2 = cvt2(lo_bf(U.z) * r1.x, hi_bf(U.z) * r1.y);
    short2 c3 = cvt2(lo_bf(U.w) * r1.z, hi_bf(U.w) * r1.w);
    bf16x8 a;
    a[0] = c0.x; a[1] = c0.y; a[2] = c1.x; a[3] = c1.y;
    a[4] = c2.x; a[5] = c2.y; a[6] = c3.x; a[7] = c3.y;
    return a;
}

// fast tanh: 1 - 2/(e^{2|x|}+1), sign restored
__device__ __forceinline__ float fast_tanh(float x) {
    float ax = fabsf(x);
    float z = __expf(2.0f * ax);
    float r = 1.0f - 2.0f / (z + 1.0f);
    return copysignf(r, x);
}

// --- init: aggbf = bf16(entity_emb), kg(=d_out) = 0 ---
__global__ void init_kernel(short4* __restrict__ aggbf, float4* __restrict__ kg,
                            const float4* __restrict__ ent, int n4) {
    int i = blockIdx.x * blockDim.x + threadIdx.x;
    if (i < n4) {
        float4 v = ent[i];
        short2 c0 = cvt2(v.x, v.y), c1 = cvt2(v.z, v.w);
        aggbf[i] = make_short4(c0.x, c0.y, c1.x, c1.y);
        kg[i] = make_float4(0.f, 0.f, 0.f, 0.f);
    }
}

// ============ one-time CSR build (counting sort by head) ============

__global__ void hist_kernel(int* __restrict__ deg, const int* __restrict__ head, int E) {
    int e = blockIdx.x * blockDim.x + threadIdx.x;
    if (e < E) atomicAdd(&deg[head[e]], 1);
}

__global__ void scan_blocks(const int* __restrict__ deg, int* __restrict__ excl,
                            int* __restrict__ bsum, int n) {
    __shared__ int wsum[4];
    int base = blockIdx.x * 1024;
    int t = threadIdx.x;
    int lane = t & 63, wid = t >> 6;
    int idx = base + t * 4;
    int v0 = (idx + 0 < n) ? deg[idx + 0] : 0;
    int v1 = (idx + 1 < n) ? deg[idx + 1] : 0;
    int v2 = (idx + 2 < n) ? deg[idx + 2] : 0;
    int v3 = (idx + 3 < n) ? deg[idx + 3] : 0;
    int s0 = v0, s1 = s0 + v1, s2 = s1 + v2, s3 = s2 + v3;
    int tsum = s3;
    int inc = tsum;
#pragma unroll
    for (int o = 1; o < 64; o <<= 1) { int u = __shfl_up(inc, o, 64); if (lane >= o) inc += u; }
    if (lane == 63) wsum[wid] = inc;
    __syncthreads();
    int woff = 0;
#pragma unroll
    for (int w = 0; w < 4; ++w) if (w < wid) woff += wsum[w];
    int texcl = woff + inc - tsum;
    if (idx + 0 < n) excl[idx + 0] = texcl;
    if (idx + 1 < n) excl[idx + 1] = texcl + s0;
    if (idx + 2 < n) excl[idx + 2] = texcl + s1;
    if (idx + 3 < n) excl[idx + 3] = texcl + s2;
    if (t == 255) bsum[blockIdx.x] = woff + inc;
}

__global__ void scan_sums(int* __restrict__ bsum, int* __restrict__ excl, int nb, int n, int E) {
    int acc = 0;
    for (int b = 0; b < nb; ++b) { int v = bsum[b]; bsum[b] = acc; acc += v; }
    excl[n] = E;
}

__global__ void scan_add(int* __restrict__ excl, const int* __restrict__ bsum, int n) {
    int i = blockIdx.x * blockDim.x + threadIdx.x;
    if (i < n) excl[i] += bsum[i >> 10];
}

// packed sorted-edge record: .x = head, .y = tail | (type<<20)
__global__ void sort_scatter(const int* __restrict__ head, const int* __restrict__ tail,
                             const int* __restrict__ etype, const int* __restrict__ offsets,
                             int* __restrict__ cursor, int2* __restrict__ spair, int E) {
    int e = blockIdx.x * blockDim.x + threadIdx.x;
    if (e >= E) return;
    int h = head[e];
    int pos = offsets[h] + atomicAdd(&cursor[h], 1);
    spair[pos] = make_int2(h, tail[e] | (etype[e] << 20));
}

// ============ per-hop kernels ============

__device__ __forceinline__ void build_bfrags(bf16x8 bfrag[2][4], const float* __restrict__ W,
                                             int lane) {
    int koff = (lane >> 4) * 8;
    int n = lane & 15;
#pragma unroll
    for (int kh = 0; kh < 2; ++kh)
#pragma unroll
        for (int nt = 0; nt < 4; ++nt) {
            bf16x8 b;
#pragma unroll
            for (int j = 0; j < 8; ++j)
                b[j] = f2bf(W[(kh * 32 + koff + j) * EMB + nt * 16 + n]);
            bfrag[kh][nt] = b;
        }
}

// --- Q = agg @ q_w via MFMA: bf16 in, bf16 out ---
__global__ void qproj_mfma_kernel(short* __restrict__ Qbf, const short* __restrict__ aggbf,
                                  const float* __restrict__ qw, int N) {
    int lane = threadIdx.x & 63;
    int gwave = blockIdx.x * (blockDim.x >> 6) + (threadIdx.x >> 6);
    int nwaves = gridDim.x * (blockDim.x >> 6);
    int row = lane & 15;
    int g = lane >> 4;
    int koff = g * 8;

    bf16x8 bfrag[2][4];
    build_bfrags(bfrag, qw, lane);

    int ntiles = (N + 15) >> 4;
    for (int tile = gwave; tile < ntiles; tile += nwaves) {
        int rIdx = min(tile * 16 + row, N - 1);
        const short* rowp = aggbf + (size_t)rIdx * EMB;
        bf16x8 a0 = *(const bf16x8*)(rowp + koff);
        bf16x8 a1 = *(const bf16x8*)(rowp + 32 + koff);
#pragma unroll
        for (int nt = 0; nt < 4; ++nt) {
            f32x4 acc = {0.f, 0.f, 0.f, 0.f};
            acc = __builtin_amdgcn_mfma_f32_16x16x32_bf16(a0, bfrag[0][nt], acc, 0, 0, 0);
            acc = __builtin_amdgcn_mfma_f32_16x16x32_bf16(a1, bfrag[1][nt], acc, 0, 0, 0);
#pragma unroll
            for (int reg = 0; reg < 4; ++reg) {
                int n2 = tile * 16 + g * 4 + reg;
                if (n2 < N) Qbf[(size_t)n2 * EMB + nt * 16 + (lane & 15)] = f2bf(acc[reg]);
            }
        }
    }
}

// --- per-edge attention via MFMA over SORTED packed edges (all-bf16 gathers) ---
__global__ void att_mfma_kernel(float* __restrict__ att,
                                const short* __restrict__ aggbf, const short* __restrict__ Qbf,
                                const float* __restrict__ eemb, const float* __restrict__ kw,
                                const int2* __restrict__ spair, int E) {
    int lane = threadIdx.x & 63;
    int gwave = blockIdx.x * (blockDim.x >> 6) + (threadIdx.x >> 6);
    int nwaves = gridDim.x * (blockDim.x >> 6);
    int row = lane & 15;
    int g = lane >> 4;

    bf16x8 bfrag[2][4];
    build_bfrags(bfrag, kw, lane);

    int ntiles = (E + 15) >> 4;
    for (int tile = gwave; tile < ntiles; tile += nwaves) {
        int eld = min(tile * 16 + row, E - 1);
        int2 pr = spair[eld];
        int h = pr.x;
        int t = pr.y & 0xFFFFF;
        unsigned r = ((unsigned)pr.y) >> 20;
        const uint4* rowa = (const uint4*)(aggbf + (size_t)t * EMB);
        const float4* rl4 = (const float4*)(eemb + (size_t)r * EMB);
        uint4 U0 = rowa[g];
        uint4 U1 = rowa[4 + g];
        float4 y0 = rl4[g * 2], y1 = rl4[g * 2 + 1];
        float4 y2 = rl4[8 + g * 2], y3 = rl4[8 + g * 2 + 1];
        bf16x8 a0 = pack8bf(U0, y0, y1);
        bf16x8 a1 = pack8bf(U1, y2, y3);

        float sums0 = 0.f, sums1 = 0.f, sums2 = 0.f, sums3 = 0.f;
#pragma unroll
        for (int nt = 0; nt < 4; ++nt) {
            f32x4 acc = {0.f, 0.f, 0.f, 0.f};
            acc = __builtin_amdgcn_mfma_f32_16x16x32_bf16(a0, bfrag[0][nt], acc, 0, 0, 0);
            acc = __builtin_amdgcn_mfma_f32_16x16x32_bf16(a1, bfrag[1][nt], acc, 0, 0, 0);
#pragma unroll
            for (int reg = 0; reg < 4; ++reg) {
                int row2 = g * 4 + reg;
                int h2 = __shfl(h, row2, 64);
                float q = bfs(Qbf[(size_t)h2 * EMB + nt * 16 + (lane & 15)]);
                float v = q * fast_tanh(acc[reg]);
                if (reg == 0) sums0 += v;
                else if (reg == 1) sums1 += v;
                else if (reg == 2) sums2 += v;
                else sums3 += v;
            }
        }
#pragma unroll
        for (int m = 1; m <= 8; m <<= 1) {
            sums0 += __shfl_xor(sums0, m, 64);
            sums1 += __shfl_xor(sums1, m, 64);
            sums2 += __shfl_xor(sums2, m, 64);
            sums3 += __shfl_xor(sums3, m, 64);
        }
#pragma unroll
        for (int reg = 0; reg < 4; ++reg) {
            int row2 = g * 4 + reg;
            int e2 = tile * 16 + row2;
            float v = (reg == 0) ? sums0 : (reg == 1) ? sums1 : (reg == 2) ? sums2 : sums3;
            if ((lane & 15) == reg && e2 < E) att[e2] = v;
        }
    }
}

// --- fused per-head softmax + weighted aggregate (bf16 gathers) + mean + l2norm + residual ---
__global__ void head_agg_kernel(short* __restrict__ aggNewBf, float* __restrict__ kg,
                                const float* __restrict__ att, const short* __restrict__ aggOldBf,
                                const float* __restrict__ eemb, const float* __restrict__ ent,
                                const int* __restrict__ offsets, const int2* __restrict__ spair,
                                int N, int R) {
    __shared__ float4 elds4[MAXREL * 16];
    __shared__ int2 pairs[4 * 64];

    int tid = threadIdx.x;
    int lane = tid & 63;
    int wid = tid >> 6;
    int RS = (R < MAXREL) ? R : MAXREL;
    for (int i = tid; i < RS * 16; i += blockDim.x) elds4[i] = ((const float4*)eemb)[i];
    __syncthreads();

    int h = blockIdx.x * (blockDim.x >> 6) + wid;
    if (h >= N) return;
    int beg = offsets[h], end = offsets[h + 1];
    int deg = end - beg;

    float m = -3.4e38f;
    for (int c = beg; c < end; c += 64) {
        int e = c + lane;
        if (e < end) m = fmaxf(m, att[e]);
    }
#pragma unroll
    for (int o = 32; o > 0; o >>= 1) m = fmaxf(m, __shfl_xor(m, o, 64));

    float ssum = 0.f;
    for (int c = beg; c < end; c += 64) {
        int e = c + lane;
        if (e < end) ssum += __expf(att[e] - m);
    }
#pragma unroll
    for (int o = 32; o > 0; o >>= 1) ssum += __shfl_xor(ssum, o, 64);
    float inv = 1.0f / ssum;

    int sub = lane >> 4;
    int q = lane & 15;
    float4 acc4 = make_float4(0.f, 0.f, 0.f, 0.f);
    int2* mypairs = &pairs[wid * 64];
    for (int c = beg; c < end; c += 64) {
        int e = c + lane;
        int nc = min(64, end - c);
        float w = 0.f; int tr = 0;
        if (e < end) {
            w = __expf(att[e] - m) * inv;
            tr = spair[e].y;
        }
        mypairs[lane] = make_int2(__float_as_int(w), tr);
        for (int j = 0; j < nc; j += 4) {
            int jj = j + sub;
            int2 p = mypairs[min(jj, nc - 1)];
            float wj = (jj < nc) ? __int_as_float(p.x) : 0.f;
            int tj = p.y & 0xFFFFF;
            unsigned rj = ((unsigned)p.y) >> 20;
            float4 ew = (rj < (unsigned)RS) ? elds4[rj * 16 + q]
                                            : ((const float4*)eemb)[(size_t)rj * 16 + q];
            uint2 X = ((const uint2*)(aggOldBf + (size_t)tj * EMB))[q];
            acc4.x += wj * ew.x * lo_bf(X.x);
            acc4.y += wj * ew.y * hi_bf(X.x);
            acc4.z += wj * ew.z * lo_bf(X.y);
            acc4.w += wj * ew.w * hi_bf(X.y);
        }
    }
#pragma unroll
    for (int o = 16; o <= 32; o <<= 1) {
        acc4.x += __shfl_xor(acc4.x, o, 64);
        acc4.y += __shfl_xor(acc4.y, o, 64);
        acc4.z += __shfl_xor(acc4.z, o, 64);
        acc4.w += __shfl_xor(acc4.w, o, 64);
    }

    float cdeg = (float)max(deg, 1);
    float4 v = make_float4(acc4.x / cdeg, acc4.y / cdeg, acc4.z / cdeg, acc4.w / cdeg);
    float ss = v.x * v.x + v.y * v.y + v.z * v.z + v.w * v.w;
#pragma unroll
    for (int o = 1; o <= 8; o <<= 1) ss += __shfl_xor(ss, o, 64);
    float rinv = 1.0f / fmaxf(sqrtf(ss), 1e-12f);
    v.x *= rinv; v.y *= rinv; v.z *= rinv; v.w *= rinv;

    if (sub == 0) {
        short2 c0 = cvt2(v.x, v.y), c1 = cvt2(v.z, v.w);
        ((short4*)aggNewBf)[(size_t)h * 16 + q] = make_short4(c0.x, c0.y, c1.x, c1.y);
        float4 kgv = ((float4*)kg)[(size_t)h * 16 + q];
        float4 ev = ((const float4*)ent)[(size_t)h * 16 + q];
        kgv.x += v.x + ev.x; kgv.y += v.y + ev.y;
        kgv.z += v.z + ev.z; kgv.w += v.w + ev.w;
        ((float4*)kg)[(size_t)h * 16 + q] = kgv;
    }
}

extern "C" void kernel_launch(void* const* d_in, const int* in_sizes, int n_in,
                              void* d_out, int out_size, void* d_ws, size_t ws_size,
                              hipStream_t stream) {
    const float* ent  = (const float*)d_in[0];
    const float* eemb = (const float*)d_in[1];
    const float* qw   = (const float*)d_in[2];
    const float* kw   = (const float*)d_in[3];
    const int* eidx  = (const int*)d_in[4];
    const int* etype = (const int*)d_in[5];

    const int N = in_sizes[0] / EMB;
    const int R = in_sizes[1] / EMB;
    const int E = in_sizes[5];
    const int* head = eidx;
    const int* tail = eidx + E;

    float* kg = (float*)d_out;

    // workspace layout
    float* att   = (float*)d_ws;                 // E f32
    int2* spair  = (int2*)(att + E);             // E int2
    int* offsets = (int*)(spair + E);            // N+1
    int* deg     = offsets + (N + 1);            // N
    int* cursor  = deg + N;                      // N
    int* bsum    = cursor + N;                   // 1024
    uintptr_t pa = ((uintptr_t)(bsum + 1024) + 15) & ~(uintptr_t)15;
    short* aggbf_a = (short*)pa;                 // N*EMB bf16 (16-B aligned)
    short* aggbf_b = aggbf_a + (size_t)N * EMB;  // N*EMB bf16
    short* Qbf     = aggbf_b + (size_t)N * EMB;  // N*EMB bf16

    const int NT = 256;
    const int WPB = NT / 64;
    const int nb = (N + 1023) / 1024;

    init_kernel<<<(N * EMB / 4 + NT - 1) / NT, NT, 0, stream>>>(
        (short4*)aggbf_a, (float4*)kg, (const float4*)ent, N * EMB / 4);
    hipMemsetAsync(deg, 0, (size_t)N * 4, stream);
    hipMemsetAsync(cursor, 0, (size_t)N * 4, stream);
    hist_kernel<<<(E + NT - 1) / NT, NT, 0, stream>>>(deg, head, E);
    scan_blocks<<<nb, NT, 0, stream>>>(deg, offsets, bsum, N);
    scan_sums<<<1, 1, 0, stream>>>(bsum, offsets, nb, N, E);
    scan_add<<<(N + NT - 1) / NT, NT, 0, stream>>>(offsets, bsum, N);
    sort_scatter<<<(E + NT - 1) / NT, NT, 0, stream>>>(head, tail, etype, offsets, cursor,
                                                       spair, E);

    short* curbf = aggbf_a;
    short* nxtbf = aggbf_b;
    for (int hop = 0; hop < 2; ++hop) {
        qproj_mfma_kernel<<<512, NT, 0, stream>>>(Qbf, curbf, qw, N);
        att_mfma_kernel<<<1024, NT, 0, stream>>>(att, curbf, Qbf, eemb, kw, spair, E);
        head_agg_kernel<<<(N + WPB - 1) / WPB, NT, 0, stream>>>(nxtbf, kg, att, curbf,
                                                                eemb, ent, offsets, spair, N, R);
        short* ts = curbf; curbf = nxtbf; nxtbf = ts;
    }
}

// Round 12
// 463.408 us; speedup vs baseline: 1.1297x; 1.1297x over previous
//
#include <hip/hip_runtime.h>
#include <math.h>

#define EMB 64
#define MAXREL 32

typedef short bf16x8 __attribute__((ext_vector_type(8)));
typedef float f32x4 __attribute__((ext_vector_type(4)));

__device__ __forceinline__ short f2bf(float f) {
    unsigned u = __float_as_uint(f);
    u += 0x7FFFu + ((u >> 16) & 1u);   // RNE
    return (short)(u >> 16);
}

#if __has_builtin(__builtin_amdgcn_cvt_pk_bf16_f32)
__device__ __forceinline__ short2 cvt2(float a, float b) {
    return __builtin_bit_cast(short2, __builtin_amdgcn_cvt_pk_bf16_f32(a, b));
}
#else
__device__ __forceinline__ short2 cvt2(float a, float b) {
    return make_short2(f2bf(a), f2bf(b));
}
#endif

// bf16 pair expansion from a packed dword (elem0 = low 16, elem1 = high 16)
__device__ __forceinline__ float lo_bf(unsigned d) { return __uint_as_float(d << 16); }
__device__ __forceinline__ float hi_bf(unsigned d) { return __uint_as_float(d & 0xffff0000u); }
__device__ __forceinline__ float bfs(short s) {
    return __uint_as_float(((unsigned)(unsigned short)s) << 16);
}

// A-fragment = bf16( bf16agg ⊙ rel_f32 )
__device__ __forceinline__ bf16x8 pack8bf(uint4 U, float4 r0, float4 r1) {
    short2 c0 = cvt2(lo_bf(U.x) * r0.x, hi_bf(U.x) * r0.y);
    short2 c1 = cvt2(lo_bf(U.y) * r0.z, hi_bf(U.y) * r0.w);
    short2 c2 = cvt2(lo_bf(U.z) * r1.x, hi_bf(U.z) * r1.y);
    short2 c3 = cvt2(lo_bf(U.w) * r1.z, hi_bf(U.w) * r1.w);
    bf16x8 a;
    a[0] = c0.x; a[1] = c0.y; a[2] = c1.x; a[3] = c1.y;
    a[4] = c2.x; a[5] = c2.y; a[6] = c3.x; a[7] = c3.y;
    return a;
}

// fast tanh: 1 - 2/(e^{2|x|}+1), sign restored
__device__ __forceinline__ float fast_tanh(float x) {
    float ax = fabsf(x);
    float z = __expf(2.0f * ax);
    float r = 1.0f - 2.0f / (z + 1.0f);
    return copysignf(r, x);
}

// --- init: aggbf = bf16(entity_emb), kg(=d_out) = 0 ---
__global__ void init_kernel(short4* __restrict__ aggbf, float4* __restrict__ kg,
                            const float4* __restrict__ ent, int n4) {
    int i = blockIdx.x * blockDim.x + threadIdx.x;
    if (i < n4) {
        float4 v = ent[i];
        short2 c0 = cvt2(v.x, v.y), c1 = cvt2(v.z, v.w);
        aggbf[i] = make_short4(c0.x, c0.y, c1.x, c1.y);
        kg[i] = make_float4(0.f, 0.f, 0.f, 0.f);
    }
}

// ============ one-time CSR build (counting sort by head) ============

__global__ void hist_kernel(int* __restrict__ deg, const int* __restrict__ head, int E) {
    int e = blockIdx.x * blockDim.x + threadIdx.x;
    if (e < E) atomicAdd(&deg[head[e]], 1);
}

__global__ void scan_blocks(const int* __restrict__ deg, int* __restrict__ excl,
                            int* __restrict__ bsum, int n) {
    __shared__ int wsum[4];
    int base = blockIdx.x * 1024;
    int t = threadIdx.x;
    int lane = t & 63, wid = t >> 6;
    int idx = base + t * 4;
    int v0 = (idx + 0 < n) ? deg[idx + 0] : 0;
    int v1 = (idx + 1 < n) ? deg[idx + 1] : 0;
    int v2 = (idx + 2 < n) ? deg[idx + 2] : 0;
    int v3 = (idx + 3 < n) ? deg[idx + 3] : 0;
    int s0 = v0, s1 = s0 + v1, s2 = s1 + v2, s3 = s2 + v3;
    int tsum = s3;
    int inc = tsum;
#pragma unroll
    for (int o = 1; o < 64; o <<= 1) { int u = __shfl_up(inc, o, 64); if (lane >= o) inc += u; }
    if (lane == 63) wsum[wid] = inc;
    __syncthreads();
    int woff = 0;
#pragma unroll
    for (int w = 0; w < 4; ++w) if (w < wid) woff += wsum[w];
    int texcl = woff + inc - tsum;
    if (idx + 0 < n) excl[idx + 0] = texcl;
    if (idx + 1 < n) excl[idx + 1] = texcl + s0;
    if (idx + 2 < n) excl[idx + 2] = texcl + s1;
    if (idx + 3 < n) excl[idx + 3] = texcl + s2;
    if (t == 255) bsum[blockIdx.x] = woff + inc;
}

__global__ void scan_sums(int* __restrict__ bsum, int* __restrict__ excl, int nb, int n, int E) {
    int acc = 0;
    for (int b = 0; b < nb; ++b) { int v = bsum[b]; bsum[b] = acc; acc += v; }
    excl[n] = E;
}

__global__ void scan_add(int* __restrict__ excl, const int* __restrict__ bsum, int n) {
    int i = blockIdx.x * blockDim.x + threadIdx.x;
    if (i < n) excl[i] += bsum[i >> 10];
}

// packed sorted-edge record: .x = head, .y = tail | (type<<20)
__global__ void sort_scatter(const int* __restrict__ head, const int* __restrict__ tail,
                             const int* __restrict__ etype, const int* __restrict__ offsets,
                             int* __restrict__ cursor, int2* __restrict__ spair, int E) {
    int e = blockIdx.x * blockDim.x + threadIdx.x;
    if (e >= E) return;
    int h = head[e];
    int pos = offsets[h] + atomicAdd(&cursor[h], 1);
    spair[pos] = make_int2(h, tail[e] | (etype[e] << 20));
}

// ============ per-hop kernels ============

__device__ __forceinline__ void build_bfrags(bf16x8 bfrag[2][4], const float* __restrict__ W,
                                             int lane) {
    int koff = (lane >> 4) * 8;
    int n = lane & 15;
#pragma unroll
    for (int kh = 0; kh < 2; ++kh)
#pragma unroll
        for (int nt = 0; nt < 4; ++nt) {
            bf16x8 b;
#pragma unroll
            for (int j = 0; j < 8; ++j)
                b[j] = f2bf(W[(kh * 32 + koff + j) * EMB + nt * 16 + n]);
            bfrag[kh][nt] = b;
        }
}

// --- Q = agg @ q_w via MFMA: bf16 in, bf16 out ---
__global__ void qproj_mfma_kernel(short* __restrict__ Qbf, const short* __restrict__ aggbf,
                                  const float* __restrict__ qw, int N) {
    int lane = threadIdx.x & 63;
    int gwave = blockIdx.x * (blockDim.x >> 6) + (threadIdx.x >> 6);
    int nwaves = gridDim.x * (blockDim.x >> 6);
    int row = lane & 15;
    int g = lane >> 4;
    int koff = g * 8;

    bf16x8 bfrag[2][4];
    build_bfrags(bfrag, qw, lane);

    int ntiles = (N + 15) >> 4;
    for (int tile = gwave; tile < ntiles; tile += nwaves) {
        int rIdx = min(tile * 16 + row, N - 1);
        const short* rowp = aggbf + (size_t)rIdx * EMB;
        bf16x8 a0 = *(const bf16x8*)(rowp + koff);
        bf16x8 a1 = *(const bf16x8*)(rowp + 32 + koff);
#pragma unroll
        for (int nt = 0; nt < 4; ++nt) {
            f32x4 acc = {0.f, 0.f, 0.f, 0.f};
            acc = __builtin_amdgcn_mfma_f32_16x16x32_bf16(a0, bfrag[0][nt], acc, 0, 0, 0);
            acc = __builtin_amdgcn_mfma_f32_16x16x32_bf16(a1, bfrag[1][nt], acc, 0, 0, 0);
#pragma unroll
            for (int reg = 0; reg < 4; ++reg) {
                int n2 = tile * 16 + g * 4 + reg;
                if (n2 < N) Qbf[(size_t)n2 * EMB + nt * 16 + (lane & 15)] = f2bf(acc[reg]);
            }
        }
    }
}

// --- per-edge attention via MFMA over SORTED packed edges (all-bf16 gathers) ---
__global__ void att_mfma_kernel(float* __restrict__ att,
                                const short* __restrict__ aggbf, const short* __restrict__ Qbf,
                                const float* __restrict__ eemb, const float* __restrict__ kw,
                                const int2* __restrict__ spair, int E) {
    int lane = threadIdx.x & 63;
    int gwave = blockIdx.x * (blockDim.x >> 6) + (threadIdx.x >> 6);
    int nwaves = gridDim.x * (blockDim.x >> 6);
    int row = lane & 15;
    int g = lane >> 4;

    bf16x8 bfrag[2][4];
    build_bfrags(bfrag, kw, lane);

    int ntiles = (E + 15) >> 4;
    for (int tile = gwave; tile < ntiles; tile += nwaves) {
        int eld = min(tile * 16 + row, E - 1);
        int2 pr = spair[eld];
        int h = pr.x;
        int t = pr.y & 0xFFFFF;
        unsigned r = ((unsigned)pr.y) >> 20;
        const uint4* rowa = (const uint4*)(aggbf + (size_t)t * EMB);
        const float4* rl4 = (const float4*)(eemb + (size_t)r * EMB);
        uint4 U0 = rowa[g];
        uint4 U1 = rowa[4 + g];
        float4 y0 = rl4[g * 2], y1 = rl4[g * 2 + 1];
        float4 y2 = rl4[8 + g * 2], y3 = rl4[8 + g * 2 + 1];
        bf16x8 a0 = pack8bf(U0, y0, y1);
        bf16x8 a1 = pack8bf(U1, y2, y3);

        float sums0 = 0.f, sums1 = 0.f, sums2 = 0.f, sums3 = 0.f;
#pragma unroll
        for (int nt = 0; nt < 4; ++nt) {
            f32x4 acc = {0.f, 0.f, 0.f, 0.f};
            acc = __builtin_amdgcn_mfma_f32_16x16x32_bf16(a0, bfrag[0][nt], acc, 0, 0, 0);
            acc = __builtin_amdgcn_mfma_f32_16x16x32_bf16(a1, bfrag[1][nt], acc, 0, 0, 0);
#pragma unroll
            for (int reg = 0; reg < 4; ++reg) {
                int row2 = g * 4 + reg;
                int h2 = __shfl(h, row2, 64);
                float q = bfs(Qbf[(size_t)h2 * EMB + nt * 16 + (lane & 15)]);
                float v = q * fast_tanh(acc[reg]);
                if (reg == 0) sums0 += v;
                else if (reg == 1) sums1 += v;
                else if (reg == 2) sums2 += v;
                else sums3 += v;
            }
        }
#pragma unroll
        for (int m = 1; m <= 8; m <<= 1) {
            sums0 += __shfl_xor(sums0, m, 64);
            sums1 += __shfl_xor(sums1, m, 64);
            sums2 += __shfl_xor(sums2, m, 64);
            sums3 += __shfl_xor(sums3, m, 64);
        }
#pragma unroll
        for (int reg = 0; reg < 4; ++reg) {
            int row2 = g * 4 + reg;
            int e2 = tile * 16 + row2;
            float v = (reg == 0) ? sums0 : (reg == 1) ? sums1 : (reg == 2) ? sums2 : sums3;
            if ((lane & 15) == reg && e2 < E) att[e2] = v;
        }
    }
}

// --- fused per-head softmax+aggregate: QUARTER-WAVE per head, 2 passes ---
// lanes q=0..15 of each quarter cover 64 dims (4/lane); aggregate accumulates
// unnormalized sum (Σ e_j · rel ⊙ agg) and divides by ssum·deg at the end.
__global__ void head_agg_kernel(short* __restrict__ aggNewBf, float* __restrict__ kg,
                                const float* __restrict__ att, const short* __restrict__ aggOldBf,
                                const float* __restrict__ eemb, const float* __restrict__ ent,
                                const int* __restrict__ offsets, const int2* __restrict__ spair,
                                int N, int R) {
    __shared__ float4 elds4[MAXREL * 16];

    int tid = threadIdx.x;
    int lane = tid & 63;
    int wid = tid >> 6;
    int RS = (R < MAXREL) ? R : MAXREL;
    for (int i = tid; i < RS * 16; i += blockDim.x) elds4[i] = ((const float4*)eemb)[i];
    __syncthreads();

    int sub = lane >> 4;     // quarter index = which head of this wave
    int q = lane & 15;       // dim quad within the head
    int h = (blockIdx.x * (blockDim.x >> 6) + wid) * 4 + sub;
    if (h >= N) return;
    int beg = offsets[h], end = offsets[h + 1];
    int deg = end - beg;

    // pass 1: max over segment (quarter-lane-parallel, stride 16)
    float m = -3.4e38f;
    for (int e = beg + q; e < end; e += 16) m = fmaxf(m, att[e]);
#pragma unroll
    for (int o = 1; o <= 8; o <<= 1) m = fmaxf(m, __shfl_xor(m, o, 64));

    // pass 2: fused exp + unnormalized aggregate
    float4 acc4 = make_float4(0.f, 0.f, 0.f, 0.f);
    float ssum = 0.f;
    int qbase = lane & 48;
    for (int c = beg; c < end; c += 16) {
        int e = c + q;
        float ev = 0.f; int tr = 0;
        if (e < end) {
            ev = __expf(att[e] - m);
            tr = spair[e].y;
        }
        ssum += ev;
        int nc = min(16, end - c);
        for (int j = 0; j < nc; ++j) {
            int src = qbase | j;
            float ej = __shfl(ev, src, 64);
            int trj = __shfl(tr, src, 64);
            int tj = trj & 0xFFFFF;
            unsigned rj = ((unsigned)trj) >> 20;
            float4 ew = (rj < (unsigned)RS) ? elds4[rj * 16 + q]
                                            : ((const float4*)eemb)[(size_t)rj * 16 + q];
            uint2 X = ((const uint2*)(aggOldBf + (size_t)tj * EMB))[q];
            acc4.x += ej * ew.x * lo_bf(X.x);
            acc4.y += ej * ew.y * hi_bf(X.x);
            acc4.z += ej * ew.z * lo_bf(X.y);
            acc4.w += ej * ew.w * hi_bf(X.y);
        }
    }
#pragma unroll
    for (int o = 1; o <= 8; o <<= 1) ssum += __shfl_xor(ssum, o, 64);

    float scale = (deg > 0) ? 1.0f / (ssum * (float)deg) : 0.f;
    float4 v = make_float4(acc4.x * scale, acc4.y * scale, acc4.z * scale, acc4.w * scale);
    float ss = v.x * v.x + v.y * v.y + v.z * v.z + v.w * v.w;
#pragma unroll
    for (int o = 1; o <= 8; o <<= 1) ss += __shfl_xor(ss, o, 64);
    float rinv = 1.0f / fmaxf(sqrtf(ss), 1e-12f);
    v.x *= rinv; v.y *= rinv; v.z *= rinv; v.w *= rinv;

    short2 c0 = cvt2(v.x, v.y), c1 = cvt2(v.z, v.w);
    ((short4*)aggNewBf)[(size_t)h * 16 + q] = make_short4(c0.x, c0.y, c1.x, c1.y);
    float4 kgv = ((float4*)kg)[(size_t)h * 16 + q];
    float4 ev2 = ((const float4*)ent)[(size_t)h * 16 + q];
    kgv.x += v.x + ev2.x; kgv.y += v.y + ev2.y;
    kgv.z += v.z + ev2.z; kgv.w += v.w + ev2.w;
    ((float4*)kg)[(size_t)h * 16 + q] = kgv;
}

extern "C" void kernel_launch(void* const* d_in, const int* in_sizes, int n_in,
                              void* d_out, int out_size, void* d_ws, size_t ws_size,
                              hipStream_t stream) {
    const float* ent  = (const float*)d_in[0];
    const float* eemb = (const float*)d_in[1];
    const float* qw   = (const float*)d_in[2];
    const float* kw   = (const float*)d_in[3];
    const int* eidx  = (const int*)d_in[4];
    const int* etype = (const int*)d_in[5];

    const int N = in_sizes[0] / EMB;
    const int R = in_sizes[1] / EMB;
    const int E = in_sizes[5];
    const int* head = eidx;
    const int* tail = eidx + E;

    float* kg = (float*)d_out;

    // workspace layout
    float* att   = (float*)d_ws;                 // E f32
    int2* spair  = (int2*)(att + E);             // E int2
    int* offsets = (int*)(spair + E);            // N+1
    int* deg     = offsets + (N + 1);            // N
    int* cursor  = deg + N;                      // N
    int* bsum    = cursor + N;                   // 1024
    uintptr_t pa = ((uintptr_t)(bsum + 1024) + 15) & ~(uintptr_t)15;
    short* aggbf_a = (short*)pa;                 // N*EMB bf16 (16-B aligned)
    short* aggbf_b = aggbf_a + (size_t)N * EMB;  // N*EMB bf16
    short* Qbf     = aggbf_b + (size_t)N * EMB;  // N*EMB bf16

    const int NT = 256;
    const int nb = (N + 1023) / 1024;

    init_kernel<<<(N * EMB / 4 + NT - 1) / NT, NT, 0, stream>>>(
        (short4*)aggbf_a, (float4*)kg, (const float4*)ent, N * EMB / 4);
    hipMemsetAsync(deg, 0, (size_t)N * 4, stream);
    hipMemsetAsync(cursor, 0, (size_t)N * 4, stream);
    hist_kernel<<<(E + NT - 1) / NT, NT, 0, stream>>>(deg, head, E);
    scan_blocks<<<nb, NT, 0, stream>>>(deg, offsets, bsum, N);
    scan_sums<<<1, 1, 0, stream>>>(bsum, offsets, nb, N, E);
    scan_add<<<(N + NT - 1) / NT, NT, 0, stream>>>(offsets, bsum, N);
    sort_scatter<<<(E + NT - 1) / NT, NT, 0, stream>>>(head, tail, etype, offsets, cursor,
                                                       spair, E);

    short* curbf = aggbf_a;
    short* nxtbf = aggbf_b;
    for (int hop = 0; hop < 2; ++hop) {
        qproj_mfma_kernel<<<512, NT, 0, stream>>>(Qbf, curbf, qw, N);
        att_mfma_kernel<<<1024, NT, 0, stream>>>(att, curbf, Qbf, eemb, kw, spair, E);
        // 4 waves/block x 4 heads/wave = 16 heads/block
        head_agg_kernel<<<(N + 15) / 16, NT, 0, stream>>>(nxtbf, kg, att, curbf,
                                                          eemb, ent, offsets, spair, N, R);
        short* ts = curbf; curbf = nxtbf; nxtbf = ts;
    }
}